// Round 4
// baseline (132.792 us; speedup 1.0000x reference)
//
#include <hip/hip_runtime.h>

// MultiHeadAttention: B=2, S=2048, D=1024, H=16, DK=64
// cast (fused) -> QKV GEMM (triple-buffer counted-vmcnt pipeline, Q pre-scaled log2 domain)
// -> causal attn (32x32 MFMA, swapped QK^T, in-register softmax, no-LDS KV, 4-way KV split)
// -> out proj GEMM (same pipeline, f32 out)

typedef unsigned short u16;
typedef unsigned int u32;
typedef __bf16 bf16x8 __attribute__((ext_vector_type(8)));
typedef float f32x4 __attribute__((ext_vector_type(4)));
typedef float f32x16 __attribute__((ext_vector_type(16)));
typedef float f32x2 __attribute__((ext_vector_type(2)));
typedef float f32x4v __attribute__((ext_vector_type(4)));
typedef u16 u16x4 __attribute__((ext_vector_type(4)));
typedef u32 u32x4 __attribute__((ext_vector_type(4)));
typedef int i32x4 __attribute__((ext_vector_type(4)));

#define B_ 2
#define S_ 2048
#define D_ 1024
#define H_ 16
#define DK_ 64

__device__ __forceinline__ u16 f2bf(float f) {
  __bf16 h = (__bf16)f;
  return __builtin_bit_cast(u16, h);
}

__device__ __forceinline__ float fexp2(float x) { return __builtin_amdgcn_exp2f(x); }

__device__ __forceinline__ f32x4 mfma16(bf16x8 a, bf16x8 b, f32x4 c) {
  return __builtin_amdgcn_mfma_f32_16x16x32_bf16(a, b, c, 0, 0, 0);
}
__device__ __forceinline__ f32x16 mfma32(bf16x8 a, bf16x8 b, f32x16 c) {
  return __builtin_amdgcn_mfma_f32_32x32x16_bf16(a, b, c, 0, 0, 0);
}

__device__ __forceinline__ u32 cvtpk(float lo, float hi) {
  u32 r;
  asm volatile("v_cvt_pk_bf16_f32 %0, %1, %2" : "=v"(r) : "v"(lo), "v"(hi));
  return r;
}
__device__ __forceinline__ u32 sx32(u32 v) { return (u32)__shfl_xor((int)v, 32, 64); }

typedef __attribute__((address_space(1))) void GV;
typedef __attribute__((address_space(3))) void LV;
__device__ __forceinline__ void gload16(const u16* g, u16* l) {
  __builtin_amdgcn_global_load_lds((GV*)g, (LV*)l, 16, 0, 0);
}

// ---------------- fused cast f32 -> bf16 ----------------
__global__ __launch_bounds__(256) void cast_all(const float* __restrict__ s0, const float* __restrict__ s1,
                                                const float* __restrict__ s2, const float* __restrict__ s3,
                                                const float* __restrict__ s4, const float* __restrict__ s5,
                                                const float* __restrict__ s6, u16* __restrict__ dst) {
  const int N0 = 1048576, N1 = 2097152, N2 = 3145728, N3 = 3407872, N4 = 3670016, N5 = 3932160, N6 = 4194304;
  int stride = gridDim.x * blockDim.x;
  for (int i = blockIdx.x * blockDim.x + threadIdx.x; i < N6; i += stride) {
    const float* src;
    int off;
    if (i < N0)      { src = s0; off = i; }
    else if (i < N1) { src = s1; off = i - N0; }
    else if (i < N2) { src = s2; off = i - N1; }
    else if (i < N3) { src = s3; off = i - N2; }
    else if (i < N4) { src = s4; off = i - N3; }
    else if (i < N5) { src = s5; off = i - N4; }
    else             { src = s6; off = i - N5; }
    f32x4v v = reinterpret_cast<const f32x4v*>(src)[off];
    u16x4 o;
    o.x = f2bf(v.x); o.y = f2bf(v.y); o.z = f2bf(v.z); o.w = f2bf(v.w);
    reinterpret_cast<u16x4*>(dst)[i] = o;
  }
}

// ---------- 128x128 GEMM mainloop: triple-buffered, counted vmcnt, 1 barrier/K-step ----------
// A[M,K] bf16 row-major, B[N,K] bf16 row-major. ldsA/ldsB each 3*128*32 u16 (24 KB).
__device__ __forceinline__ void gemm_tile_128(const u16* __restrict__ A,
                                              const u16* __restrict__ Bw,
                                              int K, int bm, int bn,
                                              f32x4 (&acc)[4][4],
                                              u16* ldsA, u16* ldsB) {
  const int tid = threadIdx.x;
  const int lane = tid & 63;
  const int w = tid >> 6;
  const int wm = w >> 1, wn = w & 1;
  const int fr = lane & 15, fq = lane >> 4;

  const u16* aBase = A + (size_t)(bm * 128) * K;
  const u16* bBase = Bw + (size_t)(bn * 128) * K;

  const int r0 = tid >> 2;
  const int cq0 = tid & 3;
  const int cs0 = (cq0 ^ (r0 & 3)) * 8;
  const int cs1 = (cq0 ^ ((r0 + 64) & 3)) * 8;

#define STAGE_G(buf, kk)                                                                          \
  do {                                                                                            \
    gload16(aBase + (size_t)r0 * K + (kk) + cs0, ldsA + (buf) * 4096 + tid * 8);                  \
    gload16(aBase + (size_t)(r0 + 64) * K + (kk) + cs1, ldsA + (buf) * 4096 + (tid + 256) * 8);   \
    gload16(bBase + (size_t)r0 * K + (kk) + cs0, ldsB + (buf) * 4096 + tid * 8);                  \
    gload16(bBase + (size_t)(r0 + 64) * K + (kk) + cs1, ldsB + (buf) * 4096 + (tid + 256) * 8);   \
  } while (0)

  STAGE_G(0, 0);
  STAGE_G(1, 32);

  const int nk = K >> 5;
  for (int t = 0; t < nk; ++t) {
    // tile t landed when <=4 of our loads remain (tile t+1 stays in flight)
    if (t + 1 < nk) { asm volatile("s_waitcnt vmcnt(4)" ::: "memory"); }
    else            { asm volatile("s_waitcnt vmcnt(0)" ::: "memory"); }
    __builtin_amdgcn_s_barrier();
    __builtin_amdgcn_sched_barrier(0);
    if (t + 2 < nk) {
      const int nb = (t + 2) % 3;
      STAGE_G(nb, (t + 2) * 32);
    }
    const u16* la = ldsA + (t % 3) * 4096;
    const u16* lb = ldsB + (t % 3) * 4096;
    bf16x8 af[4], bfv[4];
#pragma unroll
    for (int m = 0; m < 4; ++m) {
      int row = wm * 64 + m * 16 + fr;
      int cq = fq ^ (row & 3);
      af[m] = *reinterpret_cast<const bf16x8*>(la + (row * 4 + cq) * 8);
    }
#pragma unroll
    for (int n = 0; n < 4; ++n) {
      int row = wn * 64 + n * 16 + fr;
      int cq = fq ^ (row & 3);
      bfv[n] = *reinterpret_cast<const bf16x8*>(lb + (row * 4 + cq) * 8);
    }
    __builtin_amdgcn_s_setprio(1);
#pragma unroll
    for (int m = 0; m < 4; ++m)
#pragma unroll
      for (int n = 0; n < 4; ++n)
        acc[m][n] = mfma16(af[m], bfv[n], acc[m][n]);
    __builtin_amdgcn_s_setprio(0);
  }
#undef STAGE_G
}

// ---------------- QKV projection GEMM ----------------
__global__ __launch_bounds__(256) void gemm_qkv(const u16* __restrict__ Xq, const u16* __restrict__ Xk,
                                                const u16* __restrict__ Xv, const u16* __restrict__ Wq,
                                                const u16* __restrict__ Wk, const u16* __restrict__ Wv,
                                                const float* __restrict__ bq, const float* __restrict__ bk,
                                                const float* __restrict__ bv,
                                                u16* __restrict__ Qw, u16* __restrict__ Kw,
                                                u16* __restrict__ Vt) {
  __shared__ __align__(16) u16 ldsA[3 * 128 * 32];
  __shared__ __align__(16) u16 ldsB[3 * 128 * 32];
  const int z = blockIdx.z;
  const u16* A = (z == 0) ? Xq : (z == 1) ? Xk : Xv;
  const u16* W = (z == 0) ? Wq : (z == 1) ? Wk : Wv;
  const float* bias = (z == 0) ? bq : (z == 1) ? bk : bv;
  const float osc = (z == 0) ? (0.125f * 1.44269504f) : 1.0f;  // fold scale*log2e into Q

  f32x4 acc[4][4];
#pragma unroll
  for (int m = 0; m < 4; ++m)
#pragma unroll
    for (int n = 0; n < 4; ++n)
      acc[m][n] = (f32x4){0.f, 0.f, 0.f, 0.f};

  gemm_tile_128(A, W, 1024, blockIdx.y, blockIdx.x, acc, ldsA, ldsB);

  const int lane = threadIdx.x & 63;
  const int w = threadIdx.x >> 6, wm = w >> 1, wn = w & 1;
  const int fr = lane & 15, fq = lane >> 4;
#pragma unroll
  for (int m = 0; m < 4; ++m) {
#pragma unroll
    for (int n = 0; n < 4; ++n) {
      int col = blockIdx.x * 128 + wn * 64 + n * 16 + fr;
      float bcol = bias[col];
      int h = col >> 6, dk = col & 63;
#pragma unroll
      for (int j = 0; j < 4; ++j) {
        int row = blockIdx.y * 128 + wm * 64 + m * 16 + fq * 4 + j;
        float v = (acc[m][n][j] + bcol) * osc;
        u16 bb = f2bf(v);
        int b = row >> 11, s = row & (S_ - 1);
        if (z == 0)      Qw[((b * H_ + h) * S_ + s) * DK_ + dk] = bb;
        else if (z == 1) Kw[((b * H_ + h) * S_ + s) * DK_ + dk] = bb;
        else             Vt[((b * H_ + h) * DK_ + dk) * S_ + s] = bb;
      }
    }
  }
}

// ---------------- output projection GEMM ----------------
__global__ __launch_bounds__(256) void gemm_out(const u16* __restrict__ O, const u16* __restrict__ Wo,
                                                const float* __restrict__ bo, float* __restrict__ Y) {
  __shared__ __align__(16) u16 ldsA[3 * 128 * 32];
  __shared__ __align__(16) u16 ldsB[3 * 128 * 32];
  f32x4 acc[4][4];
#pragma unroll
  for (int m = 0; m < 4; ++m)
#pragma unroll
    for (int n = 0; n < 4; ++n)
      acc[m][n] = (f32x4){0.f, 0.f, 0.f, 0.f};

  gemm_tile_128(O, Wo, 1024, blockIdx.y, blockIdx.x, acc, ldsA, ldsB);

  const int lane = threadIdx.x & 63;
  const int w = threadIdx.x >> 6, wm = w >> 1, wn = w & 1;
  const int fr = lane & 15, fq = lane >> 4;
#pragma unroll
  for (int m = 0; m < 4; ++m) {
#pragma unroll
    for (int n = 0; n < 4; ++n) {
      int col = blockIdx.x * 128 + wn * 64 + n * 16 + fr;
      float bcol = bo[col];
#pragma unroll
      for (int j = 0; j < 4; ++j) {
        int row = blockIdx.y * 128 + wm * 64 + m * 16 + fq * 4 + j;
        Y[(size_t)row * D_ + col] = acc[m][n][j] + bcol;
      }
    }
  }
}

// ---------------- causal flash attention v4: 32x32 MFMA, swapped QK^T, no-LDS KV ----------------
// 1024 blocks x 4 waves. Block = (bh, 64-q-row tile). Waves split KV tiles 4-ways
// (fixed-shift softmax -> partials merge by plain addition at the end via LDS).
// Swapped QK^T (A=K, B=Q) puts q in lane&31: P is lane-local; cvt_pk + shfl_xor(32)
// builds the PV A-fragment entirely in registers. Zero barriers / zero LDS in the loop.
__global__ __launch_bounds__(256) void attn_kernel(const u16* __restrict__ Qw,
                                                   const u16* __restrict__ Kw,
                                                   const u16* __restrict__ Vt,
                                                   u16* __restrict__ O) {
  __shared__ float mbuf[2][64][64];
  __shared__ float mlbuf[2][64];

  const int id = blockIdx.x;
  const int bh = (id & 7) * 4 + ((id >> 3) & 3);  // 4 heads per XCD -> KV L2-resident
  const int qb = 31 - (id >> 5);                  // heavy blocks first (LPT)
  const int tid = threadIdx.x;
  const int w = tid >> 6;
  const int lane = tid & 63;
  const int col = lane & 31;  // q-col in QK / d-col in PV
  const int hi = lane >> 5;

  const u16* Qg = Qw + ((size_t)bh * S_ + qb * 64) * DK_;
  const u16* Kg = Kw + (size_t)bh * S_ * DK_;
  const u16* Vg = Vt + (size_t)bh * DK_ * S_;
  const int b = bh >> 4, h = bh & 15;

  // Q as B-operand fragments: qf[qt][c] = Q[qt*32+col][c*16 + hi*8 .. +7]
  bf16x8 qf[2][4];
#pragma unroll
  for (int qt = 0; qt < 2; ++qt)
#pragma unroll
    for (int c = 0; c < 4; ++c)
      qf[qt][c] = *reinterpret_cast<const bf16x8*>(Qg + (qt * 32 + col) * DK_ + c * 16 + hi * 8);

  f32x16 o[2][2];
  float ll[2] = {0.f, 0.f};
#pragma unroll
  for (int qt = 0; qt < 2; ++qt)
#pragma unroll
    for (int dt = 0; dt < 2; ++dt)
#pragma unroll
      for (int r = 0; r < 16; ++r) o[qt][dt][r] = 0.f;

  for (int t = w; t <= qb; t += 4) {
    const u16* Kt = Kg + (size_t)t * 64 * DK_;
    const u16* Vtt = Vg + t * 64;
    bf16x8 pa[2][4];  // [qt][k-chunk of 16]
#pragma unroll
    for (int kt = 0; kt < 2; ++kt) {
      bf16x8 ka[4];
#pragma unroll
      for (int c = 0; c < 4; ++c)
        ka[c] = *reinterpret_cast<const bf16x8*>(Kt + (kt * 32 + col) * DK_ + c * 16 + hi * 8);
      f32x16 s0, s1;
#pragma unroll
      for (int r = 0; r < 16; ++r) { s0[r] = 0.f; s1[r] = 0.f; }
      __builtin_amdgcn_s_setprio(1);
#pragma unroll
      for (int c = 0; c < 4; ++c) {
        s0 = mfma32(ka[c], qf[0][c], s0);
        s1 = mfma32(ka[c], qf[1][c], s1);
      }
      __builtin_amdgcn_s_setprio(0);

      if (t == qb) {  // diagonal tile: mask k > q
#pragma unroll
        for (int r = 0; r < 16; ++r) {
          int krow = kt * 32 + (r & 3) + 8 * (r >> 2) + 4 * hi;
          if (krow > col) s0[r] = -1.0e30f;          // qt=0: q = col
          if (krow > 32 + col) s1[r] = -1.0e30f;     // qt=1: q = 32+col
        }
      }
      float a0 = 0.f, a1 = 0.f;
#pragma unroll
      for (int r = 0; r < 16; ++r) {
        s0[r] = fexp2(s0[r]); a0 += s0[r];
        s1[r] = fexp2(s1[r]); a1 += s1[r];
      }
      ll[0] += a0; ll[1] += a1;

      // pack P (f32, k in regs) -> A-fragments (bf16x8, k = hi*8..): cvt_pk + cross-half shfl
#pragma unroll
      for (int qt = 0; qt < 2; ++qt) {
        const f32x16& sv = qt ? s1 : s0;
        u32 g0 = cvtpk(sv[0], sv[1]),   g1 = cvtpk(sv[2], sv[3]);
        u32 g2 = cvtpk(sv[4], sv[5]),   g3 = cvtpk(sv[6], sv[7]);
        u32 g4 = cvtpk(sv[8], sv[9]),   g5 = cvtpk(sv[10], sv[11]);
        u32 g6 = cvtpk(sv[12], sv[13]), g7 = cvtpk(sv[14], sv[15]);
        u32 t0 = sx32(g0), t1 = sx32(g1), t2 = sx32(g2), t3 = sx32(g3);
        u32 t4 = sx32(g4), t5 = sx32(g5), t6 = sx32(g6), t7 = sx32(g7);
        u32x4 lo4, hi4;
        lo4.x = hi ? t2 : g0;  lo4.y = hi ? t3 : g1;
        lo4.z = hi ? g2 : t0;  lo4.w = hi ? g3 : t1;
        hi4.x = hi ? t6 : g4;  hi4.y = hi ? t7 : g5;
        hi4.z = hi ? g6 : t4;  hi4.w = hi ? g7 : t5;
        pa[qt][kt * 2 + 0] = __builtin_bit_cast(bf16x8, lo4);
        pa[qt][kt * 2 + 1] = __builtin_bit_cast(bf16x8, hi4);
      }
    }

    // PV: O[q][d] += P[q][k] V[k][d]; V^T frags straight from global (L2-hot)
    __builtin_amdgcn_s_setprio(1);
#pragma unroll
    for (int dt = 0; dt < 2; ++dt) {
#pragma unroll
      for (int kc = 0; kc < 4; ++kc) {
        bf16x8 vb = *reinterpret_cast<const bf16x8*>(Vtt + (size_t)(dt * 32 + col) * S_ + kc * 16 + hi * 8);
        o[0][dt] = mfma32(pa[0][kc], vb, o[0][dt]);
        o[1][dt] = mfma32(pa[1][kc], vb, o[1][dt]);
      }
    }
    __builtin_amdgcn_s_setprio(0);
  }

  ll[0] += __shfl_xor(ll[0], 32, 64);
  ll[1] += __shfl_xor(ll[1], 32, 64);

  // ---- merge 4 KV-split partials via LDS (2x16KB bufs), then packed output ----
#define WRITE_PART(i)                                                         \
  do {                                                                        \
    _Pragma("unroll") for (int qt = 0; qt < 2; ++qt) {                        \
      _Pragma("unroll") for (int dt = 0; dt < 2; ++dt)                        \
        _Pragma("unroll") for (int r = 0; r < 16; ++r) {                      \
          int qrow = qt * 32 + (r & 3) + 8 * (r >> 2) + 4 * hi;               \
          mbuf[i][qrow][dt * 32 + col] = o[qt][dt][r];                        \
        }                                                                     \
      if (hi == 0) mlbuf[i][qt * 32 + col] = ll[qt];                          \
    }                                                                         \
  } while (0)
#define ADD_PART(i)                                                           \
  do {                                                                        \
    _Pragma("unroll") for (int qt = 0; qt < 2; ++qt) {                        \
      _Pragma("unroll") for (int dt = 0; dt < 2; ++dt)                        \
        _Pragma("unroll") for (int r = 0; r < 16; ++r) {                      \
          int qrow = qt * 32 + (r & 3) + 8 * (r >> 2) + 4 * hi;               \
          o[qt][dt][r] += mbuf[i][qrow][dt * 32 + col];                       \
        }                                                                     \
      ll[qt] += mlbuf[i][qt * 32 + col];                                      \
    }                                                                         \
  } while (0)

  if (w == 1) WRITE_PART(0);
  if (w == 3) WRITE_PART(1);
  __syncthreads();
  if (w == 0) ADD_PART(0);
  if (w == 2) ADD_PART(1);
  __syncthreads();
  if (w == 2) WRITE_PART(0);
  __syncthreads();
  if (w == 0) { ADD_PART(0); WRITE_PART(0); }
  __syncthreads();
#undef WRITE_PART
#undef ADD_PART

  // all waves: normalized bf16 output, 2 q-rows per iter, packed u32 stores
#pragma unroll
  for (int it = 0; it < 8; ++it) {
    int q = w * 16 + it * 2 + hi;
    f32x2 v = *reinterpret_cast<const f32x2*>(&mbuf[0][q][col * 2]);
    float linv = 1.f / mlbuf[0][q];
    u32 pk = cvtpk(v.x * linv, v.y * linv);
    *reinterpret_cast<u32*>(O + ((size_t)b * S_ + qb * 64 + q) * D_ + h * 64 + col * 2) = pk;
  }
}

extern "C" void kernel_launch(void* const* d_in, const int* in_sizes, int n_in,
                              void* d_out, int out_size, void* d_ws, size_t ws_size,
                              hipStream_t stream) {
  const float* q_in = (const float*)d_in[0];
  const float* k_in = (const float*)d_in[1];
  const float* v_in = (const float*)d_in[2];
  // d_in[3] = mask (causal, known analytically -> ignored)
  const float* wq = (const float*)d_in[4];
  const float* bq = (const float*)d_in[5];
  const float* wk = (const float*)d_in[6];
  const float* bk = (const float*)d_in[7];
  const float* wv = (const float*)d_in[8];
  const float* bv = (const float*)d_in[9];
  const float* wo = (const float*)d_in[10];
  const float* bo = (const float*)d_in[11];

  char* ws = (char*)d_ws;
  const size_t MB = 1024 * 1024;
  u16* Xq = (u16*)(ws + 0 * MB);
  u16* Xk = (u16*)(ws + 8 * MB);
  u16* Xv = (u16*)(ws + 16 * MB);
  u16* Wq = (u16*)(ws + 24 * MB);
  u16* Wk = (u16*)(ws + 26 * MB);
  u16* Wv = (u16*)(ws + 28 * MB);
  u16* Wo = (u16*)(ws + 30 * MB);
  u16* Qw = (u16*)(ws + 32 * MB);
  u16* Kw = (u16*)(ws + 40 * MB);
  u16* Vt = (u16*)(ws + 48 * MB);
  u16* Ob = (u16*)(ws + 0 * MB);  // aliases Xq (dead after gemm_qkv)

  cast_all<<<2048, 256, 0, stream>>>(q_in, k_in, v_in, wq, wk, wv, wo, (u16*)ws);
  gemm_qkv<<<dim3(8, 32, 3), 256, 0, stream>>>(Xq, Xk, Xv, Wq, Wk, Wv, bq, bk, bv, Qw, Kw, Vt);
  attn_kernel<<<1024, 256, 0, stream>>>(Qw, Kw, Vt, Ob);
  gemm_out<<<dim3(8, 32), 256, 0, stream>>>(Ob, Wo, bo, (float*)d_out);
}